// Round 2
// baseline (1181.574 us; speedup 1.0000x reference)
//
#include <hip/hip_runtime.h>
#include <stdint.h>

// ---------------- problem constants ----------------
#define HW    576          // 24*24
#define CIN   48
#define CMID  24
#define NB    1024

// output element offsets (flat fp32, return order: center,kp,reg,off,norm,pix)
#define O_CENTER 0L
#define O_KP     589824L
#define O_REG    2949120L
#define O_OFF    7667712L
#define O_NORM   12386304L
#define O_PIX    12394496L

// workspace layout (float offsets)
#define WS_WT   0        // fp32 BN-folded conv1 weights [4][48][9][24] (k-major, o contiguous)
#define WS_BS   41472    // fp32 folded bias [4][24]
#define WS_W2   41568    // fp32 conv2 weights [4][8][24]
#define WS_B2   42336    // fp32 conv2 bias [4][8]
#define WS_IDX  42368    // int32 argmax index [1024][4]

struct HeadPtrs { const float *w1,*b1,*g,*be,*m,*v,*w2,*b2; };
struct AllHeads { HeadPtrs h[4]; };

// ---------------- K0: fold BN into fp32 weights in ws ----------------
__global__ void prep_kernel(AllHeads ah, float* __restrict__ ws){
  const int head = blockIdx.x;
  const int tid  = threadIdx.x;
  const HeadPtrs hp = ah.h[head];
  __shared__ float ss[24], sb[24];
  if (tid < 24){
    float s = hp.g[tid] / sqrtf(hp.v[tid] + 1e-5f);
    ss[tid] = s;
    sb[tid] = (hp.b1[tid] - hp.m[tid]) * s + hp.be[tid];
  }
  __syncthreads();
  // wT layout: [i][k][o] -> wT[(i*9+k)*24+o] = w1[o][i][k] * scale[o]
  float* wT = ws + WS_WT + head*10368;
  for (int t = tid; t < 10368; t += blockDim.x){
    int o = t % 24; int k = (t / 24) % 9; int i = t / 216;
    wT[t] = hp.w1[(o*CIN + i)*9 + k] * ss[o];
  }
  if (tid < 24) ws[WS_BS + head*24 + tid] = sb[tid];
  const int cout = (head==0) ? 1 : (head==1) ? 4 : 8;
  for (int t = tid; t < cout*24; t += blockDim.x)
    ws[WS_W2 + head*192 + t] = hp.w2[t];
  if (tid < cout) ws[WS_B2 + head*8 + tid] = hp.b2[tid];
}

// ---------------- K1: fused conv3x3+BN+ReLU+conv1x1(+sigmoid) per (head,b) ----------------
// block = 576 threads, 1 pixel/thread; 24 input channels staged in LDS per pass (fp32,
// rows padded 24->26), two passes over the 48 input channels.
__global__ __launch_bounds__(576) void conv_kernel(
    const float* __restrict__ feat, const float* __restrict__ ws,
    int* __restrict__ widx, float* __restrict__ out)
{
  const int head = blockIdx.x;
  const int b    = blockIdx.y;
  const int tid  = threadIdx.x;
  __shared__ float simg[24*26*24];               // 59,904 B

  const int h = tid / 24;
  const int w = tid - h*24;
  const bool wl = (w > 0), wr = (w < 23);

  float acc[24];
  #pragma unroll
  for (int o = 0; o < 24; ++o) acc[o] = 0.f;

  for (int half = 0; half < 2; ++half){
    __syncthreads();                             // protect previous pass's reads
    // zero pad rows (row 0 and row 25) for the 24 staged channels
    for (int t = tid; t < 24*48; t += 576){
      int c = t / 48; int r = t - c*48;
      int row = (r < 24) ? 0 : 25;
      int col = (r < 24) ? r : r - 24;
      simg[c*624 + row*24 + col] = 0.f;
    }
    const float* fb = feat + (size_t)b * (CIN*HW) + half*(24*HW);
    const int dst = (h+1)*24 + w;
    for (int c = 0; c < 24; ++c)
      simg[c*624 + dst] = fb[c*HW + tid];        // coalesced fp32 loads
    __syncthreads();

    const float* wh = ws + WS_WT + head*10368 + half*(24*216);
    for (int ci = 0; ci < 24; ++ci){
      const int a = ci*624 + h*24 + w;           // top row of patch (padded)
      float p[9];
      #pragma unroll
      for (int dr = 0; dr < 3; ++dr){
        const int aa = a + dr*24;
        p[dr*3+0] = wl ? simg[aa-1] : 0.f;
        p[dr*3+1] = simg[aa];
        p[dr*3+2] = wr ? simg[aa+1] : 0.f;
      }
      const float* wi = wh + ci*216;             // block-uniform, 16B-aligned
      #pragma unroll
      for (int k = 0; k < 9; ++k){
        const float pk = p[k];
        const float* wk = wi + k*24;
        #pragma unroll
        for (int o = 0; o < 24; ++o)
          acc[o] = fmaf(pk, wk[o], acc[o]);
      }
    }
  }

  // folded-BN bias + relu
  const float* bSh = ws + WS_BS + head*24;
  float y[24];
  #pragma unroll
  for (int o = 0; o < 24; ++o) y[o] = fmaxf(acc[o] + bSh[o], 0.f);

  const float* w2h = ws + WS_W2 + head*192;
  const float* b2h = ws + WS_B2 + head*8;
  long obase; int cout; bool sig;
  if      (head == 0){ obase = O_CENTER; cout = 1; sig = true;  }
  else if (head == 1){ obase = O_KP;     cout = 4; sig = true;  }
  else if (head == 2){ obase = O_REG;    cout = 8; sig = false; }
  else               { obase = O_OFF;    cout = 8; sig = false; }

  float kpv[4] = {0.f, 0.f, 0.f, 0.f};
  for (int oc = 0; oc < cout; ++oc){
    float v = b2h[oc];
    #pragma unroll
    for (int o = 0; o < 24; ++o) v = fmaf(y[o], w2h[oc*24 + o], v);
    if (head == 1) kpv[oc] = v;                  // fp32 pre-sigmoid for argmax
    float ov = sig ? (1.f / (1.f + __expf(-v))) : v;
    out[obase + ((long)b*cout + oc)*HW + tid] = ov;
  }

  // kp head: block-level argmax on fp32 pre-sigmoid heatmap (first-index tiebreak)
  if (head == 1){
    __syncthreads();
    float* heat = simg;                          // reuse LDS (9216 B needed)
    #pragma unroll
    for (int n = 0; n < 4; ++n) heat[n*HW + tid] = kpv[n];
    __syncthreads();
    if (tid < 256){
      const int n = tid >> 6, lane = tid & 63;
      float bv = -1e30f; int bi = 0;
      for (int j = 0; j < 9; ++j){               // ascending p in lane -> '>' keeps first index
        int p = j*64 + lane;
        float v = heat[n*HW + p];
        if (v > bv){ bv = v; bi = p; }
      }
      #pragma unroll
      for (int off = 32; off >= 1; off >>= 1){
        float ov = __shfl_xor(bv, off, 64);
        int   oi = __shfl_xor(bi, off, 64);
        if (ov > bv || (ov == bv && oi < bi)){ bv = ov; bi = oi; }
      }
      if (lane == 0) widx[b*4 + n] = bi;
    }
  }
}

// ---------------- K2: gather offsets at argmax, emit norm & pix ----------------
__global__ void finalize_kernel(const int* __restrict__ widx, float* out){
  int t = blockIdx.x * 256 + threadIdx.x;
  if (t >= NB*4) return;
  int b = t >> 2, n = t & 3;
  int idx = widx[t];
  float mx = (float)(idx % 24);
  float my = (float)(idx / 24);
  float ox = out[O_OFF + ((long)b*8 + 2*n    )*HW + idx];
  float oy = out[O_OFF + ((long)b*8 + 2*n + 1)*HW + idx];
  float fx = (mx + ox) * 4.f - 112.f;   // SCALE=4, X0=-112
  float fy = (my + oy) * 4.f;           // Y0=0
  out[O_NORM + b*8 + 2*n    ] = (fx + 112.f) * (1.f/336.f);  // (fx-X0)/(X1-X0)
  out[O_NORM + b*8 + 2*n + 1] = fy * (1.f/224.f);            // (fy-Y0)/(Y1-Y0)
  out[O_PIX  + b*8 + 2*n    ] = fx;
  out[O_PIX  + b*8 + 2*n + 1] = fy;
}

// ---------------- launch ----------------
extern "C" void kernel_launch(void* const* d_in, const int* in_sizes, int n_in,
                              void* d_out, int out_size, void* d_ws, size_t ws_size,
                              hipStream_t stream)
{
  const float* feat = (const float*)d_in[0];
  AllHeads ah;
  for (int hd = 0; hd < 4; ++hd){
    const int base = 1 + hd*8;
    ah.h[hd].w1 = (const float*)d_in[base+0];
    ah.h[hd].b1 = (const float*)d_in[base+1];
    ah.h[hd].g  = (const float*)d_in[base+2];
    ah.h[hd].be = (const float*)d_in[base+3];
    ah.h[hd].m  = (const float*)d_in[base+4];
    ah.h[hd].v  = (const float*)d_in[base+5];
    ah.h[hd].w2 = (const float*)d_in[base+6];
    ah.h[hd].b2 = (const float*)d_in[base+7];
  }
  float* ws   = (float*)d_ws;
  int*   widx = (int*)(ws + WS_IDX);
  float* out  = (float*)d_out;

  prep_kernel    <<<dim3(4),      256, 0, stream>>>(ah, ws);
  conv_kernel    <<<dim3(4,1024), 576, 0, stream>>>(feat, ws, widx, out);
  finalize_kernel<<<dim3(16),     256, 0, stream>>>(widx, out);
}

// Round 5
// 811.638 us; speedup vs baseline: 1.4558x; 1.4558x over previous
//
#include <hip/hip_runtime.h>
#include <stdint.h>

// ---------------- problem constants ----------------
#define HW    576
#define CIN   48
#define NB    1024

// output element offsets (flat fp32: center,kp,reg,off,norm,pix)
#define O_CENTER 0L
#define O_KP     589824L
#define O_REG    2949120L
#define O_OFF    7667712L
#define O_NORM   12386304L
#define O_PIX    12394496L

// workspace byte offsets (total 174,752 B -- under the R2-proven 185,856 B)
#define WS_A1    0        // bf16 conv1 A-table [9sh][3k16][2g][96row][8ci] = 82944 B
#define WS_W2A   82944    // bf16 conv2 A-table [6k16][2g][32oc][8k]       = 6144 B
#define WS_B1A   89088    // fp32 folded bias1 [96]
#define WS_B2A   89472    // fp32 bias2 [32]
#define WS_WKPT  89600    // fp32 kp conv1 weights [ci48][k9][mid24] = 41472 B
#define WS_B1KP  131072   // fp32 [24]
#define WS_W2KP  131168   // fp32 [4][24]
#define WS_B2KP  131552   // fp32 [4]
#define WS_WOFFT 131584   // fp32 off conv1 weights [ci48][k9][mid24] = 41472 B
#define WS_B1OFF 173056   // fp32 [24]
#define WS_W2OFF 173152   // fp32 [16][24]
#define WS_B2OFF 174688   // fp32 [16]

typedef short bf16x8 __attribute__((ext_vector_type(8)));
typedef float f32x16 __attribute__((ext_vector_type(16)));

union U4B  { uint4 q; bf16x8 v; };
union U16Q { uint16_t u[8]; uint4 q; };
union U4Q  { uint16_t u[4]; uint2 q; };

__device__ __forceinline__ bf16x8 as_bf(uint4 q){ U4B u; u.q = q; return u.v; }
__device__ __forceinline__ uint16_t f2b(float f){
  union { float f; uint32_t i; } x; x.f = f;
  uint32_t r = x.i + 0x7FFFu + ((x.i >> 16) & 1u);   // RNE
  return (uint16_t)(r >> 16);
}

struct P32 {
  const float* w1[4]; const float* b1[4]; const float* g[4]; const float* be[4];
  const float* m[4];  const float* v[4];  const float* w2[4]; const float* b2[4];
};

// oc (0..20) -> head, local channel. order: center(1), kp(4), reg(8), off(8)
__device__ __forceinline__ void oc_decode(int oc, int& h, int& ch){
  if (oc == 0){ h = 0; ch = 0; }
  else if (oc < 5){ h = 1; ch = oc - 1; }
  else if (oc < 13){ h = 2; ch = oc - 5; }
  else { h = 3; ch = oc - 13; }
}

// ---------------- K0: build all tables in ws ----------------
__global__ void prep_kernel(P32 P, char* __restrict__ wsb){
  const int tid = threadIdx.x;
  __shared__ float sc[96], bfold[96];
  if (tid < 96){
    int h = tid / 24, o = tid % 24;
    float s = P.g[h][o] / sqrtf(P.v[h][o] + 1e-5f);   // R2's known-good fold
    sc[tid] = s;
    bfold[tid] = (P.b1[h][o] - P.m[h][o]) * s + P.be[h][o];
  }
  __syncthreads();
  uint16_t* A1 = (uint16_t*)(wsb + WS_A1);
  for (int t = tid; t < 41472; t += 256){
    int j = t & 7, slot = t >> 3;
    int row = slot % 96, sk = slot / 96;
    int g = sk & 1, k3 = (sk >> 1) % 3, sh = (sk >> 1) / 3;
    int ci = k3*16 + g*8 + j;
    int h = row / 24, o = row % 24;
    A1[t] = f2b(P.w1[h][(o*CIN + ci)*9 + sh] * sc[row]);
  }
  uint16_t* W2A = (uint16_t*)(wsb + WS_W2A);
  for (int t = tid; t < 3072; t += 256){
    int j = t & 7, slot = t >> 3;
    int oc = slot & 31, kg = slot >> 5;
    int k = kg*8 + j;
    float val = 0.f;
    if (oc < 21){
      int h, ch; oc_decode(oc, h, ch);
      int hk = k / 24, o = k % 24;
      if (hk == h) val = P.w2[h][ch*24 + o];
    }
    W2A[t] = f2b(val);
  }
  float* B1A = (float*)(wsb + WS_B1A);
  if (tid < 96) B1A[tid] = bfold[tid];
  float* B2A = (float*)(wsb + WS_B2A);
  if (tid < 32){
    float v = 0.f;
    if (tid < 21){ int h, ch; oc_decode(tid, h, ch); v = P.b2[h][ch]; }
    B2A[tid] = v;
  }
  // kp exact tables (fp32), [ci][k][mid]
  float* WKPT = (float*)(wsb + WS_WKPT);
  for (int t = tid; t < 10368; t += 256){
    int o = t % 24, k = (t/24) % 9, ci = t / 216;
    WKPT[t] = P.w1[1][(o*CIN + ci)*9 + k] * sc[24 + o];
  }
  if (tid < 24) ((float*)(wsb + WS_B1KP))[tid] = bfold[24 + tid];
  if (tid < 96) ((float*)(wsb + WS_W2KP))[tid] = P.w2[1][tid];
  if (tid < 4)  ((float*)(wsb + WS_B2KP))[tid] = P.b2[1][tid];
  // off exact tables (fp32), [ci][k][mid]
  float* WOFFT = (float*)(wsb + WS_WOFFT);
  for (int t = tid; t < 10368; t += 256){
    int o = t % 24, k = (t/24) % 9, ci = t / 216;
    WOFFT[t] = P.w1[3][(o*CIN + ci)*9 + k] * sc[72 + o];
  }
  if (tid < 24)  ((float*)(wsb + WS_B1OFF))[tid] = bfold[72 + tid];
  for (int t = tid; t < 384; t += 256) ((float*)(wsb + WS_W2OFF))[t] = P.w2[3][t];
  if (tid < 16)  ((float*)(wsb + WS_B2OFF))[tid] = P.b2[3][tid];
}

// ---------------- K1: MFMA conv per batch (dense outputs only) ----------------
__global__ __launch_bounds__(576) void conv_main(
    const float* __restrict__ feat, const char* __restrict__ wsb,
    float* __restrict__ out)
{
  __shared__ __align__(16) char smem[60000];
  const int b = blockIdx.x, tid = threadIdx.x;
  const int wave = tid >> 6, lane = tid & 63;
  const int q = lane >> 5, l31 = lane & 31;

  if (tid < 294){                                 // zero border row y'=0, col x'=0
    int cib = tid / 49, r = tid % 49;
    int slot = cib*625 + ((r < 25) ? r : (r - 24)*25);
    *(uint4*)(smem + slot*16) = make_uint4(0,0,0,0);
  }
  {
    const float* fb = feat + (size_t)b * (CIN*HW);
    int p = tid, py = p / 24, px = p % 24;
    int sbase = (py+1)*25 + (px+1);
    for (int cib = 0; cib < 6; ++cib){
      U16Q t8;
      #pragma unroll
      for (int j = 0; j < 8; ++j) t8.u[j] = f2b(fb[(cib*8 + j)*HW + p]);
      *(uint4*)(smem + (cib*625 + sbase)*16) = t8.q;
    }
  }
  __syncthreads();

  f32x16 acc[3][2] = {};
  const int p0 = wave*64 + l31, p1 = p0 + 32;
  const int py0 = p0/24, px0 = p0%24, py1 = p1/24, px1 = p1%24;
  const uint4* A1 = (const uint4*)(wsb + WS_A1);
  const uint4 zz = make_uint4(0,0,0,0);

  for (int sh = 0; sh < 9; ++sh){
    const int ky = sh / 3, kx = sh % 3;
    const int yb0 = py0 + ky, xb0 = px0 + kx;
    const int yb1 = py1 + ky, xb1 = px1 + kx;
    const bool v0 = (yb0 < 25) && (xb0 < 25);
    const bool v1 = (yb1 < 25) && (xb1 < 25);
    const int so0 = yb0*25 + xb0, so1 = yb1*25 + xb1;
    #pragma unroll
    for (int k3 = 0; k3 < 3; ++k3){
      const int cib = k3*2 + q;
      uint4 r0 = *(const uint4*)(smem + (cib*625 + (v0 ? so0 : 0))*16);
      uint4 r1 = *(const uint4*)(smem + (cib*625 + (v1 ? so1 : 0))*16);
      r0 = v0 ? r0 : zz;
      r1 = v1 ? r1 : zz;
      const bf16x8 bf0 = as_bf(r0), bf1 = as_bf(r1);
      const int abase = ((sh*3 + k3)*2 + q)*96 + l31;
      #pragma unroll
      for (int mt = 0; mt < 3; ++mt){
        const bf16x8 af = as_bf(A1[abase + mt*32]);
        acc[mt][0] = __builtin_amdgcn_mfma_f32_32x32x16_bf16(af, bf0, acc[mt][0], 0, 0, 0);
        acc[mt][1] = __builtin_amdgcn_mfma_f32_32x32x16_bf16(af, bf1, acc[mt][1], 0, 0, 0);
      }
    }
  }
  __syncthreads();                                // image dead; reuse LDS

  const float* B1A = (const float*)(wsb + WS_B1A);
  const float* B2A = (const float*)(wsb + WS_B2A);
  const uint4* W2A = (const uint4*)(wsb + WS_W2A);
  char* ybuf = smem + wave*6144;

  #pragma unroll
  for (int st2 = 0; st2 < 2; ++st2){
    const int p = st2 ? p1 : p0;
    #pragma unroll
    for (int mt = 0; mt < 3; ++mt){
      #pragma unroll
      for (int rg = 0; rg < 4; ++rg){
        const int chanbase = mt*32 + rg*8 + q*4;
        const float* bp = B1A + chanbase;
        U4Q t4;
        #pragma unroll
        for (int r0 = 0; r0 < 4; ++r0){
          float y = acc[mt][st2][rg*4 + r0] + bp[r0];
          t4.u[r0] = f2b(fmaxf(y, 0.f));
        }
        *(uint2*)(ybuf + ((mt*4 + rg)*32 + l31)*16 + q*8) = t4.q;
      }
    }
    f32x16 c2 = {};
    #pragma unroll
    for (int k6 = 0; k6 < 6; ++k6){
      const bf16x8 yf = as_bf(*(const uint4*)(ybuf + ((k6*2 + q)*32 + l31)*16));
      const bf16x8 wf = as_bf(W2A[(k6*2 + q)*32 + l31]);
      c2 = __builtin_amdgcn_mfma_f32_32x32x16_bf16(wf, yf, c2, 0, 0, 0);
    }
    #pragma unroll
    for (int r = 0; r < 16; ++r){
      const int oc = (r & 3) + 8*(r >> 2) + 4*q;
      if (oc < 21){
        float v = c2[r] + B2A[oc];
        long base; int sig;
        if (oc == 0){ base = O_CENTER + (long)b*HW; sig = 1; }
        else if (oc < 5){ base = O_KP + ((long)b*4 + (oc-1))*HW; sig = 1; }
        else if (oc < 13){ base = O_REG + ((long)b*8 + (oc-5))*HW; sig = 0; }
        else { base = O_OFF + ((long)b*8 + (oc-13))*HW; sig = 0; }
        out[base + p] = sig ? (1.f / (1.f + __expf(-v))) : v;
      }
    }
  }
}

// ---------------- K2: exact fp32 kp head: logits -> argmax -> exact offsets -> norm/pix ----
// R2-cloned math (bit-identical fmaf ordering: ci-major, k-inner). 8-ci LDS passes
// (19,968 B -> 3 blocks/CU). heat[4][576] aliased onto dead image region.
__global__ __launch_bounds__(576) void kp_exact(
    const float* __restrict__ feat, const char* __restrict__ wsb,
    float* __restrict__ out)
{
  __shared__ float simg[8*26*24];                 // 19,968 B
  const int b = blockIdx.x, tid = threadIdx.x;
  const int h = tid / 24, w = tid - h*24;
  const bool wl = (w > 0), wr = (w < 23);
  const float* fb = feat + (size_t)b * (CIN*HW);
  const float* WKPT = (const float*)(wsb + WS_WKPT);

  float acc[24];
  #pragma unroll
  for (int o = 0; o < 24; ++o) acc[o] = 0.f;

  for (int pass = 0; pass < 6; ++pass){
    __syncthreads();                              // protect previous pass reads
    if (tid < 384){                               // zero pad rows 0 and 25
      int c = tid / 48, r = tid - c*48;
      int row = (r < 24) ? 0 : 25;
      int col = (r < 24) ? r : r - 24;
      simg[c*624 + row*24 + col] = 0.f;
    }
    const int dst = (h+1)*24 + w;
    #pragma unroll
    for (int c = 0; c < 8; ++c)
      simg[c*624 + dst] = fb[(pass*8 + c)*HW + tid];
    __syncthreads();

    for (int c8 = 0; c8 < 8; ++c8){
      const int a = c8*624 + h*24 + w;
      float p[9];
      #pragma unroll
      for (int dr = 0; dr < 3; ++dr){
        const int aa = a + dr*24;
        p[dr*3+0] = wl ? simg[aa-1] : 0.f;
        p[dr*3+1] = simg[aa];
        p[dr*3+2] = wr ? simg[aa+1] : 0.f;
      }
      const float* wi = WKPT + (pass*8 + c8)*216;
      #pragma unroll
      for (int k = 0; k < 9; ++k){
        const float pk = p[k];
        const float* wk = wi + k*24;
        #pragma unroll
        for (int o = 0; o < 24; ++o)
          acc[o] = fmaf(pk, wk[o], acc[o]);
      }
    }
  }
  __syncthreads();                                // all passes done; simg dead

  // logits (pre-sigmoid) into heat[4][576] (aliased on simg)
  const float* B1KP = (const float*)(wsb + WS_B1KP);
  const float* W2KP = (const float*)(wsb + WS_W2KP);
  const float* B2KP = (const float*)(wsb + WS_B2KP);
  float* heat = simg;
  {
    float y[24];
    #pragma unroll
    for (int o = 0; o < 24; ++o) y[o] = fmaxf(acc[o] + B1KP[o], 0.f);
    #pragma unroll
    for (int n = 0; n < 4; ++n){
      float v = B2KP[n];
      #pragma unroll
      for (int o = 0; o < 24; ++o) v = fmaf(y[o], W2KP[n*24 + o], v);
      heat[n*HW + tid] = v;
    }
  }
  __syncthreads();

  if (tid < 256){
    const int n = tid >> 6, lane = tid & 63;
    // argmax, first-index tie-break (ascending p, strict '>')
    float bv = -1e30f; int bi = 0;
    for (int j = 0; j < 9; ++j){
      int p = j*64 + lane;
      float v = heat[n*HW + p];
      if (v > bv){ bv = v; bi = p; }
    }
    #pragma unroll
    for (int off = 32; off >= 1; off >>= 1){
      float ov = __shfl_xor(bv, off, 64);
      int   oi = __shfl_xor(bi, off, 64);
      if (ov > bv || (ov == bv && oi < bi)){ bv = ov; bi = oi; }
    }
    const int bp = bi, py = bp / 24, px = bp % 24;

    // exact off-head mids at pixel bp: lanes 0..23, one mid each
    const float* WOFFT = (const float*)(wsb + WS_WOFFT);
    const float* B1OFF = (const float*)(wsb + WS_B1OFF);
    float ymid = 0.f;
    if (lane < 24){
      float s = 0.f;
      for (int ci = 0; ci < CIN; ++ci){
        const float* wv = WOFFT + ci*216 + lane;  // [ci][k][mid]
        const float* xb = fb + ci*HW;
        #pragma unroll
        for (int k = 0; k < 9; ++k){
          int yy = py + k/3 - 1, xx = px + k%3 - 1;
          if (yy >= 0 && yy < 24 && xx >= 0 && xx < 24)
            s = fmaf(xb[yy*24 + xx], wv[k*24], s);
        }
      }
      ymid = fmaxf(s + B1OFF[lane], 0.f);
    }
    // lane 0 gathers mids via shuffles, forms ox/oy, writes norm & pix
    float ym[24];
    #pragma unroll
    for (int sl = 0; sl < 24; ++sl) ym[sl] = __shfl(ymid, sl, 64);
    if (lane == 0){
      const float* W2OFF = (const float*)(wsb + WS_W2OFF);
      const float* B2OFF = (const float*)(wsb + WS_B2OFF);
      float ox = B2OFF[2*n], oy = B2OFF[2*n + 1];
      for (int o = 0; o < 24; ++o){
        ox = fmaf(ym[o], W2OFF[(2*n)*24 + o], ox);
        oy = fmaf(ym[o], W2OFF[(2*n + 1)*24 + o], oy);
      }
      float fx = ((float)px + ox) * 4.f - 112.f;  // SCALE=4, X0=-112
      float fy = ((float)py + oy) * 4.f;          // Y0=0
      out[O_NORM + b*8 + 2*n    ] = (fx + 112.f) * (1.f/336.f);
      out[O_NORM + b*8 + 2*n + 1] = fy * (1.f/224.f);
      out[O_PIX  + b*8 + 2*n    ] = fx;
      out[O_PIX  + b*8 + 2*n + 1] = fy;
    }
  }
}

// ---------------- launch ----------------
extern "C" void kernel_launch(void* const* d_in, const int* in_sizes, int n_in,
                              void* d_out, int out_size, void* d_ws, size_t ws_size,
                              hipStream_t stream)
{
  const float* feat = (const float*)d_in[0];
  P32 P;
  for (int h = 0; h < 4; ++h){
    const int base = 1 + h*8;
    P.w1[h] = (const float*)d_in[base+0];
    P.b1[h] = (const float*)d_in[base+1];
    P.g[h]  = (const float*)d_in[base+2];
    P.be[h] = (const float*)d_in[base+3];
    P.m[h]  = (const float*)d_in[base+4];
    P.v[h]  = (const float*)d_in[base+5];
    P.w2[h] = (const float*)d_in[base+6];
    P.b2[h] = (const float*)d_in[base+7];
  }
  char* wsb = (char*)d_ws;
  float* out = (float*)d_out;

  prep_kernel<<<dim3(1),   256, 0, stream>>>(P, wsb);
  conv_main  <<<dim3(NB),  576, 0, stream>>>(feat, wsb, out);
  kp_exact   <<<dim3(NB),  576, 0, stream>>>(feat, wsb, out);
}